// Round 1
// baseline (226.966 us; speedup 1.0000x reference)
//
#include <hip/hip_runtime.h>
#include <math.h>

#define EPS 1e-8f

constexpr int B = 2;
constexpr int N = 512;
constexpr int M = 512;
constexpr int D = 256;
constexpr int H = 64;   // heads = D/4

// ---------------------------------------------------------------------------
// Kernel A: row = one (b, n) pair; computes P = x @ W^T + b, then normalizes
// each consecutive group of 4 as a quaternion. grid.y: 0 = vision, 1 = text.
// ---------------------------------------------------------------------------
__global__ void proj_norm_kernel(const float* __restrict__ vis,
                                 const float* __restrict__ txt,
                                 const float* __restrict__ Wv,
                                 const float* __restrict__ bv,
                                 const float* __restrict__ Wt,
                                 const float* __restrict__ bt,
                                 float* __restrict__ qv,
                                 float* __restrict__ qt)
{
    const int row   = blockIdx.x;            // 0 .. B*N-1
    const int which = blockIdx.y;            // 0 vision, 1 text
    const float* x    = (which == 0 ? vis : txt) + row * D;
    const float* Wmat = (which == 0 ? Wv  : Wt);
    const float* bias = (which == 0 ? bv  : bt);
    float*       q    = (which == 0 ? qv  : qt) + row * D;

    __shared__ __align__(16) float xs[D];
    __shared__ float ps[D];
    const int t = threadIdx.x;               // 0..255 == output dim d

    xs[t] = x[t];
    __syncthreads();

    const float4* W4  = (const float4*)(Wmat + t * D);
    const float4* xs4 = (const float4*)xs;
    float acc = bias[t];
    #pragma unroll 8
    for (int k = 0; k < D / 4; ++k) {
        float4 w  = W4[k];
        float4 xv = xs4[k];
        acc = fmaf(w.x, xv.x, acc);
        acc = fmaf(w.y, xv.y, acc);
        acc = fmaf(w.z, xv.z, acc);
        acc = fmaf(w.w, xv.w, acc);
    }
    ps[t] = acc;
    __syncthreads();

    const int hq = (t >> 2) << 2;            // base of my quaternion group
    float a0 = ps[hq + 0], a1 = ps[hq + 1], a2 = ps[hq + 2], a3 = ps[hq + 3];
    float nrm = sqrtf(a0 * a0 + a1 * a1 + a2 * a2 + a3 * a3);
    q[t] = acc / (nrm + EPS);
}

// ---------------------------------------------------------------------------
// Block-wide reductions (256 threads = 4 waves of 64)
// ---------------------------------------------------------------------------
__device__ __forceinline__ float block_reduce_max(float v, float* red)
{
    __syncthreads();                         // protect red[] reuse
    #pragma unroll
    for (int off = 32; off > 0; off >>= 1)
        v = fmaxf(v, __shfl_down(v, off, 64));
    const int wid  = threadIdx.x >> 6;
    const int lane = threadIdx.x & 63;
    if (lane == 0) red[wid] = v;
    __syncthreads();
    if (threadIdx.x == 0)
        red[0] = fmaxf(fmaxf(red[0], red[1]), fmaxf(red[2], red[3]));
    __syncthreads();
    return red[0];
}

__device__ __forceinline__ float block_reduce_sum(float v, float* red)
{
    __syncthreads();
    #pragma unroll
    for (int off = 32; off > 0; off >>= 1)
        v += __shfl_down(v, off, 64);
    const int wid  = threadIdx.x >> 6;
    const int lane = threadIdx.x & 63;
    if (lane == 0) red[wid] = v;
    __syncthreads();
    if (threadIdx.x == 0)
        red[0] = red[0] + red[1] + red[2] + red[3];
    __syncthreads();
    return red[0];
}

// ---------------------------------------------------------------------------
// Kernel B: one block per (b, n) row. Computes logits over all m (mean over
// heads of interference / sqrt(D)), then softmax, writes attn and attn^T.
//
// interference(w) = (w+eps)^2 / ((w+eps)^2 + max(1 - w^2, 0))
// where w = dot4(q_v, q_t)  [unit quaternions: |vec|^2 = 1 - w^2 exactly]
// ---------------------------------------------------------------------------
__global__ void attn_kernel(const float* __restrict__ qv,
                            const float* __restrict__ qt,
                            float* __restrict__ attn,
                            float* __restrict__ attnT)
{
    const int row = blockIdx.x;              // b*N + n
    const int b   = row >> 9;
    const int n   = row & (N - 1);
    const int t   = threadIdx.x;             // 256 threads

    __shared__ __align__(16) float qvs[D];
    __shared__ float L[M];
    __shared__ float red[4];

    qvs[t] = qv[row * D + t];
    __syncthreads();

    const float4* qv4 = (const float4*)qvs;
    float lv[2];
    #pragma unroll
    for (int mm = 0; mm < 2; ++mm) {
        const int m = t + mm * 256;
        const float4* qt4 = (const float4*)(qt + (b * M + m) * D);
        float acc = 0.f;
        #pragma unroll 4
        for (int h = 0; h < H; ++h) {
            float4 a = qv4[h];
            float4 c = qt4[h];
            float w = a.x * c.x + a.y * c.y + a.z * c.z + a.w * c.w;
            float te = w + EPS;
            float t2 = te * te;
            float vec = fmaxf(1.f - w * w, 0.f);
            acc += t2 / (t2 + vec);
        }
        lv[mm] = acc * (1.0f / 1024.0f);     // mean over 64 heads, / sqrt(256)
        L[m] = lv[mm];
    }

    float mx = block_reduce_max(fmaxf(lv[0], lv[1]), red);

    float e0 = expf(lv[0] - mx);
    float e1 = expf(lv[1] - mx);
    float sum = block_reduce_sum(e0 + e1, red);
    float inv = 1.f / sum;

    const float a0 = e0 * inv;
    const float a1 = e1 * inv;
    attn[row * M + t]        = a0;
    attn[row * M + t + 256]  = a1;
    attnT[(b * M + t)       * N + n] = a0;
    attnT[(b * M + t + 256) * N + n] = a1;
}

// ---------------------------------------------------------------------------
// Kernel C: outputs. grid.y==0: out_vision[b,n,:] = vis + h * attn(row) @ txt
//           grid.y==1: out_text  [b,m,:] = txt + h * attnT(row) @ vis
// ---------------------------------------------------------------------------
__global__ void out_kernel(const float* __restrict__ vis,
                           const float* __restrict__ txt,
                           const float* __restrict__ attn,
                           const float* __restrict__ attnT,
                           const float* __restrict__ hptr,
                           float* __restrict__ outv,
                           float* __restrict__ outt)
{
    const int row   = blockIdx.x;            // b*512 + r
    const int which = blockIdx.y;
    const int b     = row >> 9;
    const int t     = threadIdx.x;           // 256 threads == d
    const float hv  = hptr[0];

    __shared__ float s[M];
    const float* arow = (which == 0 ? attn : attnT) + row * M;
    s[t]       = arow[t];
    s[t + 256] = arow[t + 256];
    __syncthreads();

    const float* src = (which == 0 ? txt : vis) + b * (512 * D);
    float acc = 0.f;
    #pragma unroll 8
    for (int m = 0; m < M; ++m)
        acc = fmaf(s[m], src[m * D + t], acc);

    const float* base = (which == 0 ? vis : txt) + row * D;
    float* out = (which == 0 ? outv : outt) + row * D;
    out[t] = base[t] + hv * acc;
}

// ---------------------------------------------------------------------------
extern "C" void kernel_launch(void* const* d_in, const int* in_sizes, int n_in,
                              void* d_out, int out_size, void* d_ws, size_t ws_size,
                              hipStream_t stream)
{
    const float* vis = (const float*)d_in[0];
    const float* txt = (const float*)d_in[1];
    const float* Wv  = (const float*)d_in[2];
    const float* bv  = (const float*)d_in[3];
    const float* Wt  = (const float*)d_in[4];
    const float* bt  = (const float*)d_in[5];
    const float* h   = (const float*)d_in[6];

    float* outv = (float*)d_out;                  // B*N*D
    float* outt = (float*)d_out + B * N * D;      // B*M*D

    float* ws    = (float*)d_ws;
    float* qv    = ws;                            // B*N*D    = 262144
    float* qt    = ws + 262144;                   // B*M*D    = 262144
    float* attn  = ws + 524288;                   // B*N*M    = 524288
    float* attnT = ws + 1048576;                  // B*M*N    = 524288

    proj_norm_kernel<<<dim3(B * N, 2), 256, 0, stream>>>(vis, txt, Wv, bv, Wt, bt, qv, qt);
    attn_kernel<<<dim3(B * N), 256, 0, stream>>>(qv, qt, attn, attnT);
    out_kernel<<<dim3(B * N, 2), 256, 0, stream>>>(vis, txt, attn, attnT, h, outv, outt);
}

// Round 3
// 129.252 us; speedup vs baseline: 1.7560x; 1.7560x over previous
//
#include <hip/hip_runtime.h>
#include <math.h>

#define EPS 1e-8f

constexpr int B = 2;
constexpr int N = 512;
constexpr int M = 512;
constexpr int D = 256;

#define FMA4(acc, s, wv)                   \
    acc.x = fmaf(s, wv.x, acc.x);          \
    acc.y = fmaf(s, wv.y, acc.y);          \
    acc.z = fmaf(s, wv.z, acc.z);          \
    acc.w = fmaf(s, wv.w, acc.w);

// ---------------------------------------------------------------------------
// Kernel A: proj + quaternion normalize.  C = normalize4(X @ W^T + b).
// Tiles: 32 rows x 64 cols, KT=32.  grid (32, 4, 2), block 256.
// Thread: rows {2tr, 2tr+1}, cols 4tc..4tc+3 (exactly one quaternion/row).
// ---------------------------------------------------------------------------
__global__ __launch_bounds__(256) void proj_norm_kernel(
    const float* __restrict__ vis, const float* __restrict__ txt,
    const float* __restrict__ Wv, const float* __restrict__ bv,
    const float* __restrict__ Wt, const float* __restrict__ bt,
    float* __restrict__ qv, float* __restrict__ qt)
{
    const int which = blockIdx.z;
    const float* X    = which == 0 ? vis : txt;
    const float* W    = which == 0 ? Wv : Wt;
    const float* bias = which == 0 ? bv : bt;
    float*       Q    = which == 0 ? qv : qt;
    const int r0 = blockIdx.x * 32;
    const int c0 = blockIdx.y * 64;
    const int t  = threadIdx.x;
    const int tr = t >> 4;   // 0..15
    const int tc = t & 15;   // 0..15

    __shared__ __align__(16) float As[32][36];   // [row][k]
    __shared__ __align__(16) float Ws[32][68];   // [k][col] (transposed W)

    float4 b4 = *(const float4*)(bias + c0 + 4 * tc);
    float4 acc0 = b4, acc1 = b4;

    for (int k0 = 0; k0 < D; k0 += 32) {
        {   // stage A tile (coalesced)
            const int rr = t >> 3, k4 = t & 7;
            *(float4*)&As[rr][4 * k4] =
                *(const float4*)(X + (r0 + rr) * D + k0 + 4 * k4);
        }
        {   // stage W tile transposed: Ws[kk][c] = W[c0+c][k0+kk]
            const int c = t >> 2, kk4 = t & 3;
            float4 wq = *(const float4*)(W + (c0 + c) * D + k0 + 4 * kk4);
            Ws[4 * kk4 + 0][c] = wq.x;
            Ws[4 * kk4 + 1][c] = wq.y;
            Ws[4 * kk4 + 2][c] = wq.z;
            Ws[4 * kk4 + 3][c] = wq.w;
        }
        __syncthreads();
        #pragma unroll
        for (int k4 = 0; k4 < 8; ++k4) {
            float4 a0 = *(float4*)&As[2 * tr][4 * k4];
            float4 a1 = *(float4*)&As[2 * tr + 1][4 * k4];
            float4 w0 = *(float4*)&Ws[4 * k4 + 0][4 * tc];
            float4 w1 = *(float4*)&Ws[4 * k4 + 1][4 * tc];
            float4 w2 = *(float4*)&Ws[4 * k4 + 2][4 * tc];
            float4 w3 = *(float4*)&Ws[4 * k4 + 3][4 * tc];
            FMA4(acc0, a0.x, w0) FMA4(acc0, a0.y, w1)
            FMA4(acc0, a0.z, w2) FMA4(acc0, a0.w, w3)
            FMA4(acc1, a1.x, w0) FMA4(acc1, a1.y, w1)
            FMA4(acc1, a1.z, w2) FMA4(acc1, a1.w, w3)
        }
        __syncthreads();
    }

    {   // normalize quaternion, row 2tr
        float nrm = sqrtf(acc0.x*acc0.x + acc0.y*acc0.y + acc0.z*acc0.z + acc0.w*acc0.w);
        float inv = 1.f / (nrm + EPS);
        float4 q = {acc0.x*inv, acc0.y*inv, acc0.z*inv, acc0.w*inv};
        *(float4*)(Q + (r0 + 2*tr) * D + c0 + 4*tc) = q;
    }
    {   // row 2tr+1
        float nrm = sqrtf(acc1.x*acc1.x + acc1.y*acc1.y + acc1.z*acc1.z + acc1.w*acc1.w);
        float inv = 1.f / (nrm + EPS);
        float4 q = {acc1.x*inv, acc1.y*inv, acc1.z*inv, acc1.w*inv};
        *(float4*)(Q + (r0 + 2*tr + 1) * D + c0 + 4*tc) = q;
    }
}

// ---------------------------------------------------------------------------
// Kernel B: attention logits + softmax.  4 n-rows/block (wave=row), m staged
// in LDS tiles of 32.  Lane = (m, head-parity); shfl_xor(32) merges parities.
// interference(w) = (w+eps)^2 / ((w+eps)^2 + max(1-w^2,0))  [no trig needed]
// ---------------------------------------------------------------------------
__global__ __launch_bounds__(256) void attn_kernel(
    const float* __restrict__ qv, const float* __restrict__ qt,
    float* __restrict__ attn)
{
    const int n0   = blockIdx.x * 4;     // global row (b*N+n), 256 blocks
    const int b    = n0 >> 9;
    const int t    = threadIdx.x;
    const int r    = t >> 6;             // wave = local row 0..3
    const int lane = t & 63;
    const int mloc = lane & 31;
    const int par  = lane >> 5;          // head parity

    __shared__ __align__(16) float qvs[4][260];
    __shared__ __align__(16) float qts[32][260];

    {   // stage qv rows: 4 x 64 float4
        int j = t >> 6, h4 = t & 63;
        *(float4*)&qvs[j][4 * h4] = *(const float4*)(qv + (n0 + j) * D + 4 * h4);
    }

    float lv[16];
    #pragma unroll
    for (int tile = 0; tile < 16; ++tile) {
        __syncthreads();                 // qts reuse + first-iter qvs visibility
        #pragma unroll
        for (int i = 0; i < 8; ++i) {    // stage qt tile: 32 rows x 64 f4, coalesced
            int gid = t + 256 * i;
            int mm = gid >> 6, h4 = gid & 63;
            *(float4*)&qts[mm][4 * h4] =
                *(const float4*)(qt + (b * M + tile * 32 + mm) * D + 4 * h4);
        }
        __syncthreads();

        float acc = 0.f;
        for (int i = 0; i < 32; ++i) {
            int hh = 2 * i + par;
            float4 a = *(float4*)&qvs[r][4 * hh];
            float4 c = *(float4*)&qts[mloc][4 * hh];
            float w  = a.x*c.x + a.y*c.y + a.z*c.z + a.w*c.w;
            float te = w + EPS;
            float t2 = te * te;
            float vec = fmaxf(fmaf(-w, w, 1.f), 0.f);
            acc += t2 * __builtin_amdgcn_rcpf(t2 + vec);
        }
        acc += __shfl_xor(acc, 32, 64);  // merge head parities
        lv[tile] = acc * (1.0f / 1024.0f);   // /64 heads /sqrt(256)
    }

    // softmax over 512 m per row (each m duplicated across parity lanes)
    float mx = lv[0];
    #pragma unroll
    for (int i = 1; i < 16; ++i) mx = fmaxf(mx, lv[i]);
    #pragma unroll
    for (int off = 32; off >= 1; off >>= 1) mx = fmaxf(mx, __shfl_xor(mx, off, 64));
    float e[16];
    float s = 0.f;
    #pragma unroll
    for (int i = 0; i < 16; ++i) { e[i] = __expf(lv[i] - mx); s += e[i]; }
    #pragma unroll
    for (int off = 32; off >= 1; off >>= 1) s += __shfl_xor(s, off, 64);
    float inv = 2.0f / s;                // s double-counts every m
    if (par == 0) {
        #pragma unroll
        for (int tile = 0; tile < 16; ++tile)
            attn[(n0 + r) * M + tile * 32 + mloc] = e[tile] * inv;
    }
}

// ---------------------------------------------------------------------------
// Kernel C: out = base + h * (A @ S).  which=0: A=attn, S=txt, base=vis.
// which=1: A=attn^T (staged transposed), S=vis, base=txt.
// Tiles 32x64, KT=32, K=512.  grid (16, 4, 4), block 256.
// ---------------------------------------------------------------------------
__global__ __launch_bounds__(256) void out_kernel(
    const float* __restrict__ vis, const float* __restrict__ txt,
    const float* __restrict__ attn, const float* __restrict__ hptr,
    float* __restrict__ outv, float* __restrict__ outt)
{
    const int z = blockIdx.z;
    const int b = z & 1, which = z >> 1;
    const int r0 = blockIdx.x * 32;
    const int c0 = blockIdx.y * 64;
    const int t  = threadIdx.x;
    const int tr = t >> 4, tc = t & 15;
    const float hv = hptr[0];

    const float* S    = (which == 0 ? txt : vis) + b * 512 * D;
    const float* base = (which == 0 ? vis : txt) + b * 512 * D;
    float*       out  = (which == 0 ? outv : outt) + b * 512 * D;

    __shared__ __align__(16) float As[32][36];   // [row][k]
    __shared__ __align__(16) float Bs[32][68];   // [k][col]

    float4 acc0 = {0.f, 0.f, 0.f, 0.f}, acc1 = {0.f, 0.f, 0.f, 0.f};

    for (int k0 = 0; k0 < 512; k0 += 32) {
        if (which == 0) {                // A rows = attn rows (coalesced)
            const int rr = t >> 3, k4 = t & 7;
            *(float4*)&As[rr][4 * k4] =
                *(const float4*)(attn + (b * N + r0 + rr) * M + k0 + 4 * k4);
        } else {                         // A rows = attn columns: transpose-stage
            const int kk = t >> 3, m4 = t & 7;
            float4 a = *(const float4*)(attn + (b * N + k0 + kk) * M + r0 + 4 * m4);
            As[4 * m4 + 0][kk] = a.x;
            As[4 * m4 + 1][kk] = a.y;
            As[4 * m4 + 2][kk] = a.z;
            As[4 * m4 + 3][kk] = a.w;
        }
        #pragma unroll
        for (int u = 0; u < 2; ++u) {    // stage S tile: 32 k x 64 c (coalesced)
            int id = t + 256 * u;
            int kk = id >> 4, c4 = id & 15;
            *(float4*)&Bs[kk][4 * c4] =
                *(const float4*)(S + (k0 + kk) * D + c0 + 4 * c4);
        }
        __syncthreads();
        #pragma unroll
        for (int k4 = 0; k4 < 8; ++k4) {
            float4 a0 = *(float4*)&As[2 * tr][4 * k4];
            float4 a1 = *(float4*)&As[2 * tr + 1][4 * k4];
            float4 w0 = *(float4*)&Bs[4 * k4 + 0][4 * tc];
            float4 w1 = *(float4*)&Bs[4 * k4 + 1][4 * tc];
            float4 w2 = *(float4*)&Bs[4 * k4 + 2][4 * tc];
            float4 w3 = *(float4*)&Bs[4 * k4 + 3][4 * tc];
            FMA4(acc0, a0.x, w0) FMA4(acc0, a0.y, w1)
            FMA4(acc0, a0.z, w2) FMA4(acc0, a0.w, w3)
            FMA4(acc1, a1.x, w0) FMA4(acc1, a1.y, w1)
            FMA4(acc1, a1.z, w2) FMA4(acc1, a1.w, w3)
        }
        __syncthreads();
    }

    {
        int r = r0 + 2 * tr;
        float4 bs = *(const float4*)(base + r * D + c0 + 4 * tc);
        float4 o = {fmaf(hv, acc0.x, bs.x), fmaf(hv, acc0.y, bs.y),
                    fmaf(hv, acc0.z, bs.z), fmaf(hv, acc0.w, bs.w)};
        *(float4*)(out + r * D + c0 + 4 * tc) = o;
    }
    {
        int r = r0 + 2 * tr + 1;
        float4 bs = *(const float4*)(base + r * D + c0 + 4 * tc);
        float4 o = {fmaf(hv, acc1.x, bs.x), fmaf(hv, acc1.y, bs.y),
                    fmaf(hv, acc1.z, bs.z), fmaf(hv, acc1.w, bs.w)};
        *(float4*)(out + r * D + c0 + 4 * tc) = o;
    }
}

// ---------------------------------------------------------------------------
extern "C" void kernel_launch(void* const* d_in, const int* in_sizes, int n_in,
                              void* d_out, int out_size, void* d_ws, size_t ws_size,
                              hipStream_t stream)
{
    const float* vis = (const float*)d_in[0];
    const float* txt = (const float*)d_in[1];
    const float* Wv  = (const float*)d_in[2];
    const float* bv  = (const float*)d_in[3];
    const float* Wt  = (const float*)d_in[4];
    const float* bt  = (const float*)d_in[5];
    const float* h   = (const float*)d_in[6];

    float* outv = (float*)d_out;                  // B*N*D
    float* outt = (float*)d_out + B * N * D;      // B*M*D

    float* ws   = (float*)d_ws;
    float* qv   = ws;                             // B*N*D    = 262144
    float* qt   = ws + 262144;                    // B*M*D    = 262144
    float* attn = ws + 524288;                    // B*N*M    = 524288

    proj_norm_kernel<<<dim3(32, 4, 2), 256, 0, stream>>>(vis, txt, Wv, bv, Wt, bt, qv, qt);
    attn_kernel<<<dim3(256), 256, 0, stream>>>(qv, qt, attn);
    out_kernel<<<dim3(16, 4, 4), 256, 0, stream>>>(vis, txt, attn, h, outv, outt);
}

// Round 4
// 120.590 us; speedup vs baseline: 1.8821x; 1.0718x over previous
//
#include <hip/hip_runtime.h>
#include <math.h>

#define EPS 1e-8f

constexpr int B = 2;
constexpr int N = 512;
constexpr int M = 512;
constexpr int D = 256;

typedef short bf16x8 __attribute__((ext_vector_type(8)));
typedef float f32x4  __attribute__((ext_vector_type(4)));

// fp32 -> bf16 bits, round-to-nearest-even
__device__ __forceinline__ short f2bf(float f) {
    union { float fv; unsigned u; } v; v.fv = f;
    unsigned r = v.u + 0x7fffu + ((v.u >> 16) & 1u);
    return (short)(r >> 16);
}
__device__ __forceinline__ bf16x8 pack8(float4 a, float4 b) {
    bf16x8 p;
    p[0] = f2bf(a.x); p[1] = f2bf(a.y); p[2] = f2bf(a.z); p[3] = f2bf(a.w);
    p[4] = f2bf(b.x); p[5] = f2bf(b.y); p[6] = f2bf(b.z); p[7] = f2bf(b.w);
    return p;
}

// ---------------------------------------------------------------------------
// Kernel A (MFMA): Q = normalize4(X @ W^T + bias).  X:[1024][256], W:[256][256]
// row-major [out_d][k] — both operands load with NO transpose.
// Block: 256 thr = 4 waves (2x2), tile 64 rows x 64 cols, ktile 32.
// grid (16, 4, 2).  A-frag lane: [m=lane&15][k=quad*8+j]; B-frag: [n][k];
// D-frag: col=lane&15, row=quad*4+reg  [verified layouts, learn_hip m89/m91].
// ---------------------------------------------------------------------------
__global__ __launch_bounds__(256) void proj_mfma_kernel(
    const float* __restrict__ vis, const float* __restrict__ txt,
    const float* __restrict__ Wv, const float* __restrict__ bv,
    const float* __restrict__ Wt, const float* __restrict__ bt,
    float* __restrict__ qv, float* __restrict__ qt)
{
    const int which = blockIdx.z;
    const float* X    = which == 0 ? vis : txt;
    const float* W    = which == 0 ? Wv : Wt;
    const float* bias = which == 0 ? bv : bt;
    float*       Q    = which == 0 ? qv : qt;

    const int r0 = blockIdx.x * 64;
    const int c0 = blockIdx.y * 64;
    const int t    = threadIdx.x;
    const int lane = t & 63;
    const int wave = t >> 6;
    const int wr = (wave >> 1) * 32, wc = (wave & 1) * 32;
    const int mrow = lane & 15, quad = lane >> 4;

    __shared__ __align__(16) short As[64][40];   // [row][k], stride 80B: 2-way banks
    __shared__ __align__(16) short Bs[64][40];   // [col][k]

    f32x4 acc[2][2] = {};

    const int srow = t >> 2;   // 0..63
    const int skp  = t & 3;    // 0..3 -> 8 k each

    for (int k0 = 0; k0 < D; k0 += 32) {
        const float* xp = X + (r0 + srow) * D + k0 + 8 * skp;
        const float* wp = W + (c0 + srow) * D + k0 + 8 * skp;
        float4 xa = *(const float4*)xp, xb = *(const float4*)(xp + 4);
        float4 wa = *(const float4*)wp, wb = *(const float4*)(wp + 4);
        __syncthreads();
        *(bf16x8*)&As[srow][8 * skp] = pack8(xa, xb);
        *(bf16x8*)&Bs[srow][8 * skp] = pack8(wa, wb);
        __syncthreads();
        bf16x8 a0 = *(bf16x8*)&As[wr + mrow][8 * quad];
        bf16x8 a1 = *(bf16x8*)&As[wr + 16 + mrow][8 * quad];
        bf16x8 b0 = *(bf16x8*)&Bs[wc + mrow][8 * quad];
        bf16x8 b1 = *(bf16x8*)&Bs[wc + 16 + mrow][8 * quad];
        acc[0][0] = __builtin_amdgcn_mfma_f32_16x16x32_bf16(a0, b0, acc[0][0], 0, 0, 0);
        acc[0][1] = __builtin_amdgcn_mfma_f32_16x16x32_bf16(a0, b1, acc[0][1], 0, 0, 0);
        acc[1][0] = __builtin_amdgcn_mfma_f32_16x16x32_bf16(a1, b0, acc[1][0], 0, 0, 0);
        acc[1][1] = __builtin_amdgcn_mfma_f32_16x16x32_bf16(a1, b1, acc[1][1], 0, 0, 0);
    }

    float bj0 = bias[c0 + wc + mrow];
    float bj1 = bias[c0 + wc + 16 + mrow];
    #pragma unroll
    for (int i = 0; i < 2; ++i) {
        #pragma unroll
        for (int j = 0; j < 2; ++j) {
            const int col = c0 + wc + 16 * j + mrow;
            const float bb = j == 0 ? bj0 : bj1;
            #pragma unroll
            for (int reg = 0; reg < 4; ++reg) {
                const int row = r0 + wr + 16 * i + quad * 4 + reg;
                float v = acc[i][j][reg] + bb;
                // quaternion = 4 adjacent cols = lanes differing in bits 0,1
                float s = v * v;
                s += __shfl_xor(s, 1, 64);
                s += __shfl_xor(s, 2, 64);
                float inv = 1.f / (sqrtf(s) + EPS);
                Q[row * D + col] = v * inv;
            }
        }
    }
}

// ---------------------------------------------------------------------------
// Kernel B: attention logits + softmax.  4 n-rows/block (wave=row), m staged
// in LDS tiles of 32.  Lane = (m, head-parity); shfl_xor(32) merges parities.
// For unit quats: interference == w^2 exactly (|vec|^2 = 1 - w^2) — no rcp.
// ---------------------------------------------------------------------------
__global__ __launch_bounds__(256) void attn_kernel(
    const float* __restrict__ qv, const float* __restrict__ qt,
    float* __restrict__ attn)
{
    const int n0   = blockIdx.x * 4;     // global row (b*N+n), 256 blocks
    const int b    = n0 >> 9;
    const int t    = threadIdx.x;
    const int r    = t >> 6;             // wave = local row 0..3
    const int lane = t & 63;
    const int mloc = lane & 31;
    const int par  = lane >> 5;          // head parity

    __shared__ __align__(16) float qvs[4][260];
    __shared__ __align__(16) float qts[32][260];

    {   // stage qv rows: 4 x 64 float4
        int j = t >> 6, h4 = t & 63;
        *(float4*)&qvs[j][4 * h4] = *(const float4*)(qv + (n0 + j) * D + 4 * h4);
    }

    float lv[16];
    #pragma unroll
    for (int tile = 0; tile < 16; ++tile) {
        __syncthreads();                 // qts reuse + first-iter qvs visibility
        #pragma unroll
        for (int i = 0; i < 8; ++i) {    // stage qt tile: 32 rows x 64 f4, coalesced
            int gid = t + 256 * i;
            int mm = gid >> 6, h4 = gid & 63;
            *(float4*)&qts[mm][4 * h4] =
                *(const float4*)(qt + (b * M + tile * 32 + mm) * D + 4 * h4);
        }
        __syncthreads();

        float acc = 0.f;
        #pragma unroll 8
        for (int i = 0; i < 32; ++i) {
            int hh = 2 * i + par;
            float4 a = *(float4*)&qvs[r][4 * hh];
            float4 c = *(float4*)&qts[mloc][4 * hh];
            float w  = a.x * c.x + a.y * c.y + a.z * c.z + a.w * c.w;
            acc = fmaf(w, w, acc);       // interference == w^2 for unit quats
        }
        acc += __shfl_xor(acc, 32, 64);  // merge head parities
        lv[tile] = acc * (1.0f / 1024.0f);   // /64 heads /sqrt(256)
    }

    // softmax over 512 m per row (each m duplicated across parity lanes)
    float mx = lv[0];
    #pragma unroll
    for (int i = 1; i < 16; ++i) mx = fmaxf(mx, lv[i]);
    #pragma unroll
    for (int off = 32; off >= 1; off >>= 1) mx = fmaxf(mx, __shfl_xor(mx, off, 64));
    float e[16];
    float s = 0.f;
    #pragma unroll
    for (int i = 0; i < 16; ++i) { e[i] = __expf(lv[i] - mx); s += e[i]; }
    #pragma unroll
    for (int off = 32; off >= 1; off >>= 1) s += __shfl_xor(s, off, 64);
    float inv = 2.0f / s;                // s double-counts every m
    if (par == 0) {
        #pragma unroll
        for (int tile = 0; tile < 16; ++tile)
            attn[(n0 + r) * M + tile * 32 + mloc] = e[tile] * inv;
    }
}

// ---------------------------------------------------------------------------
// Kernel C (MFMA): out = base + h * (A @ S).
// which=0: A=attn [n][m], S=txt, base=vis (rows=n, K=m)
// which=1: A=attn^T (transpose-staged), S=vis, base=txt (rows=m, K=n)
// B operand needs [d][k] = S^T: transpose-staged from S rows.
// Block 256 thr, tile 64 rows x 64 d-cols, K=512.  grid (8, 4, 4).
// ---------------------------------------------------------------------------
__global__ __launch_bounds__(256) void out_mfma_kernel(
    const float* __restrict__ vis, const float* __restrict__ txt,
    const float* __restrict__ attn, const float* __restrict__ hptr,
    float* __restrict__ outv, float* __restrict__ outt)
{
    const int z = blockIdx.z;
    const int b = z & 1, which = z >> 1;
    const int r0 = blockIdx.x * 64;
    const int c0 = blockIdx.y * 64;
    const int t    = threadIdx.x;
    const int lane = t & 63;
    const int wave = t >> 6;
    const int wr = (wave >> 1) * 32, wc = (wave & 1) * 32;
    const int mrow = lane & 15, quad = lane >> 4;
    const float hv = hptr[0];

    const float* Ablk = attn + b * N * M;
    const float* S    = (which == 0 ? txt : vis) + b * 512 * D;
    const float* base = (which == 0 ? vis : txt) + b * 512 * D;
    float*       out  = (which == 0 ? outv : outt) + b * 512 * D;

    __shared__ __align__(16) short As[64][40];   // [row][k]
    __shared__ __align__(16) short Bs[64][40];   // [d][k]

    f32x4 acc[2][2] = {};

    for (int k0 = 0; k0 < 512; k0 += 32) {
        __syncthreads();
        if (which == 0) {                // A rows = attn rows: direct stage
            const int srow = t >> 2, skp = t & 3;
            const float* ap = Ablk + (r0 + srow) * M + k0 + 8 * skp;
            float4 a0 = *(const float4*)ap, a1 = *(const float4*)(ap + 4);
            *(bf16x8*)&As[srow][8 * skp] = pack8(a0, a1);
        } else {                         // A rows = attn cols: transpose-stage
            const int kk = t >> 3, mg = t & 7;
            const float* ap = Ablk + (k0 + kk) * M + r0 + 8 * mg;
            float4 a0 = *(const float4*)ap, a1 = *(const float4*)(ap + 4);
            As[8 * mg + 0][kk] = f2bf(a0.x);
            As[8 * mg + 1][kk] = f2bf(a0.y);
            As[8 * mg + 2][kk] = f2bf(a0.z);
            As[8 * mg + 3][kk] = f2bf(a0.w);
            As[8 * mg + 4][kk] = f2bf(a1.x);
            As[8 * mg + 5][kk] = f2bf(a1.y);
            As[8 * mg + 6][kk] = f2bf(a1.z);
            As[8 * mg + 7][kk] = f2bf(a1.w);
        }
        {                                // B: S^T transpose-stage
            const int kk = t >> 3, cg = t & 7;
            const float* sp = S + (k0 + kk) * D + c0 + 8 * cg;
            float4 s0 = *(const float4*)sp, s1 = *(const float4*)(sp + 4);
            Bs[8 * cg + 0][kk] = f2bf(s0.x);
            Bs[8 * cg + 1][kk] = f2bf(s0.y);
            Bs[8 * cg + 2][kk] = f2bf(s0.z);
            Bs[8 * cg + 3][kk] = f2bf(s0.w);
            Bs[8 * cg + 4][kk] = f2bf(s1.x);
            Bs[8 * cg + 5][kk] = f2bf(s1.y);
            Bs[8 * cg + 6][kk] = f2bf(s1.z);
            Bs[8 * cg + 7][kk] = f2bf(s1.w);
        }
        __syncthreads();
        bf16x8 a0 = *(bf16x8*)&As[wr + mrow][8 * quad];
        bf16x8 a1 = *(bf16x8*)&As[wr + 16 + mrow][8 * quad];
        bf16x8 b0 = *(bf16x8*)&Bs[wc + mrow][8 * quad];
        bf16x8 b1 = *(bf16x8*)&Bs[wc + 16 + mrow][8 * quad];
        acc[0][0] = __builtin_amdgcn_mfma_f32_16x16x32_bf16(a0, b0, acc[0][0], 0, 0, 0);
        acc[0][1] = __builtin_amdgcn_mfma_f32_16x16x32_bf16(a0, b1, acc[0][1], 0, 0, 0);
        acc[1][0] = __builtin_amdgcn_mfma_f32_16x16x32_bf16(a1, b0, acc[1][0], 0, 0, 0);
        acc[1][1] = __builtin_amdgcn_mfma_f32_16x16x32_bf16(a1, b1, acc[1][1], 0, 0, 0);
    }

    #pragma unroll
    for (int i = 0; i < 2; ++i) {
        #pragma unroll
        for (int j = 0; j < 2; ++j) {
            const int col = c0 + wc + 16 * j + mrow;
            #pragma unroll
            for (int reg = 0; reg < 4; ++reg) {
                const int row = r0 + wr + 16 * i + quad * 4 + reg;
                out[row * D + col] = fmaf(hv, acc[i][j][reg], base[row * D + col]);
            }
        }
    }
}

// ---------------------------------------------------------------------------
extern "C" void kernel_launch(void* const* d_in, const int* in_sizes, int n_in,
                              void* d_out, int out_size, void* d_ws, size_t ws_size,
                              hipStream_t stream)
{
    const float* vis = (const float*)d_in[0];
    const float* txt = (const float*)d_in[1];
    const float* Wv  = (const float*)d_in[2];
    const float* bv  = (const float*)d_in[3];
    const float* Wt  = (const float*)d_in[4];
    const float* bt  = (const float*)d_in[5];
    const float* h   = (const float*)d_in[6];

    float* outv = (float*)d_out;                  // B*N*D
    float* outt = (float*)d_out + B * N * D;      // B*M*D

    float* ws   = (float*)d_ws;
    float* qv   = ws;                             // B*N*D    = 262144
    float* qt   = ws + 262144;                    // B*M*D    = 262144
    float* attn = ws + 524288;                    // B*N*M    = 524288

    proj_mfma_kernel<<<dim3(16, 4, 2), 256, 0, stream>>>(vis, txt, Wv, bv, Wt, bt, qv, qt);
    attn_kernel<<<dim3(256), 256, 0, stream>>>(qv, qt, attn);
    out_mfma_kernel<<<dim3(8, 4, 4), 256, 0, stream>>>(vis, txt, attn, h, outv, outt);
}

// Round 5
// 113.898 us; speedup vs baseline: 1.9927x; 1.0588x over previous
//
#include <hip/hip_runtime.h>
#include <math.h>

#define EPS 1e-8f

constexpr int B = 2;
constexpr int N = 512;
constexpr int M = 512;
constexpr int D = 256;

typedef short bf16x8 __attribute__((ext_vector_type(8)));
typedef float f32x4  __attribute__((ext_vector_type(4)));

// fp32 -> bf16 bits, round-to-nearest-even
__device__ __forceinline__ short f2bf(float f) {
    union { float fv; unsigned u; } v; v.fv = f;
    unsigned r = v.u + 0x7fffu + ((v.u >> 16) & 1u);
    return (short)(r >> 16);
}
__device__ __forceinline__ bf16x8 pack8(float4 a, float4 b) {
    bf16x8 p;
    p[0] = f2bf(a.x); p[1] = f2bf(a.y); p[2] = f2bf(a.z); p[3] = f2bf(a.w);
    p[4] = f2bf(b.x); p[5] = f2bf(b.y); p[6] = f2bf(b.z); p[7] = f2bf(b.w);
    return p;
}

// ---------------------------------------------------------------------------
// Kernel 1 (MFMA): Q = normalize4(X @ W^T + bias).  Unchanged from round 4.
// Block 256 = 4 waves (2x2), tile 64x64, ktile 32.  grid (16, 4, 2).
// ---------------------------------------------------------------------------
__global__ __launch_bounds__(256) void proj_mfma_kernel(
    const float* __restrict__ vis, const float* __restrict__ txt,
    const float* __restrict__ Wv, const float* __restrict__ bv,
    const float* __restrict__ Wt, const float* __restrict__ bt,
    float* __restrict__ qv, float* __restrict__ qt)
{
    const int which = blockIdx.z;
    const float* X    = which == 0 ? vis : txt;
    const float* W    = which == 0 ? Wv : Wt;
    const float* bias = which == 0 ? bv : bt;
    float*       Q    = which == 0 ? qv : qt;

    const int r0 = blockIdx.x * 64;
    const int c0 = blockIdx.y * 64;
    const int t    = threadIdx.x;
    const int lane = t & 63;
    const int wave = t >> 6;
    const int wr = (wave >> 1) * 32, wc = (wave & 1) * 32;
    const int mrow = lane & 15, quad = lane >> 4;

    __shared__ __align__(16) short As[64][40];
    __shared__ __align__(16) short Bs[64][40];

    f32x4 acc[2][2] = {};

    const int srow = t >> 2;
    const int skp  = t & 3;

    for (int k0 = 0; k0 < D; k0 += 32) {
        const float* xp = X + (r0 + srow) * D + k0 + 8 * skp;
        const float* wp = W + (c0 + srow) * D + k0 + 8 * skp;
        float4 xa = *(const float4*)xp, xb = *(const float4*)(xp + 4);
        float4 wa = *(const float4*)wp, wb = *(const float4*)(wp + 4);
        __syncthreads();
        *(bf16x8*)&As[srow][8 * skp] = pack8(xa, xb);
        *(bf16x8*)&Bs[srow][8 * skp] = pack8(wa, wb);
        __syncthreads();
        bf16x8 a0 = *(bf16x8*)&As[wr + mrow][8 * quad];
        bf16x8 a1 = *(bf16x8*)&As[wr + 16 + mrow][8 * quad];
        bf16x8 b0 = *(bf16x8*)&Bs[wc + mrow][8 * quad];
        bf16x8 b1 = *(bf16x8*)&Bs[wc + 16 + mrow][8 * quad];
        acc[0][0] = __builtin_amdgcn_mfma_f32_16x16x32_bf16(a0, b0, acc[0][0], 0, 0, 0);
        acc[0][1] = __builtin_amdgcn_mfma_f32_16x16x32_bf16(a0, b1, acc[0][1], 0, 0, 0);
        acc[1][0] = __builtin_amdgcn_mfma_f32_16x16x32_bf16(a1, b0, acc[1][0], 0, 0, 0);
        acc[1][1] = __builtin_amdgcn_mfma_f32_16x16x32_bf16(a1, b1, acc[1][1], 0, 0, 0);
    }

    float bj0 = bias[c0 + wc + mrow];
    float bj1 = bias[c0 + wc + 16 + mrow];
    #pragma unroll
    for (int i = 0; i < 2; ++i) {
        #pragma unroll
        for (int j = 0; j < 2; ++j) {
            const int col = c0 + wc + 16 * j + mrow;
            const float bb = j == 0 ? bj0 : bj1;
            #pragma unroll
            for (int reg = 0; reg < 4; ++reg) {
                const int row = r0 + wr + 16 * i + quad * 4 + reg;
                float v = acc[i][j][reg] + bb;
                float s = v * v;
                s += __shfl_xor(s, 1, 64);
                s += __shfl_xor(s, 2, 64);
                float inv = 1.f / (sqrtf(s) + EPS);
                Q[row * D + col] = v * inv;
            }
        }
    }
}

// ---------------------------------------------------------------------------
// Kernel 2: expand each unit quaternion into its 16 pairwise products (bf16).
// q: 2048 rows x 256 (qv rows 0..1023, qt rows 1024..2047, contiguous).
// exp: 2048 rows x 1024.  Thread = (row, head).  grid 512 x 256.
// ---------------------------------------------------------------------------
__global__ __launch_bounds__(256) void expand_kernel(
    const float* __restrict__ q, short* __restrict__ expq)
{
    const int gid = blockIdx.x * 256 + threadIdx.x;   // 0..131071
    const int row = gid >> 6, hh = gid & 63;
    float4 v = *(const float4*)(q + row * 256 + 4 * hh);
    float c[4] = {v.x, v.y, v.z, v.w};
    short p[16];
    #pragma unroll
    for (int i = 0; i < 4; ++i)
        #pragma unroll
        for (int j = 0; j < 4; ++j)
            p[4 * i + j] = f2bf(c[i] * c[j]);
    *(bf16x8*)(expq + row * 1024 + 16 * hh)     = *(bf16x8*)&p[0];
    *(bf16x8*)(expq + row * 1024 + 16 * hh + 8) = *(bf16x8*)&p[8];
}

// ---------------------------------------------------------------------------
// Kernel 3 (MFMA): logits.  Lg[b][n][m] = <expv[b*512+n], expt[b*512+m>]/1024.
// K = 1024.  Tile 32(n) x 64(m), 4 waves 2x2 of 16x32.  grid (16, 8, 2).
// ---------------------------------------------------------------------------
__global__ __launch_bounds__(256) void logits_kernel(
    const short* __restrict__ expv, const short* __restrict__ expt,
    float* __restrict__ Lg)
{
    const int b  = blockIdx.z;
    const int r0 = blockIdx.x * 32;
    const int c0 = blockIdx.y * 64;
    const int t = threadIdx.x, lane = t & 63, wave = t >> 6;
    const int wr = (wave >> 1) * 16, wc = (wave & 1) * 32;
    const int mrow = lane & 15, quad = lane >> 4;

    __shared__ __align__(16) short As[32][40];
    __shared__ __align__(16) short Bs[64][40];

    const short* Arow = expv + (b * 512 + r0) * 1024;
    const short* Brow = expt + (b * 512 + c0) * 1024;

    f32x4 acc0 = {}, acc1 = {};
    for (int k0 = 0; k0 < 1024; k0 += 32) {
        __syncthreads();
        if (t < 128) {
            const int row = t >> 2, ch = t & 3;
            *(bf16x8*)&As[row][8 * ch] =
                *(const bf16x8*)(Arow + row * 1024 + k0 + 8 * ch);
        }
        {
            const int row = t >> 2, ch = t & 3;
            *(bf16x8*)&Bs[row][8 * ch] =
                *(const bf16x8*)(Brow + row * 1024 + k0 + 8 * ch);
        }
        __syncthreads();
        bf16x8 a  = *(bf16x8*)&As[wr + mrow][8 * quad];
        bf16x8 b0 = *(bf16x8*)&Bs[wc + mrow][8 * quad];
        bf16x8 b1 = *(bf16x8*)&Bs[wc + 16 + mrow][8 * quad];
        acc0 = __builtin_amdgcn_mfma_f32_16x16x32_bf16(a, b0, acc0, 0, 0, 0);
        acc1 = __builtin_amdgcn_mfma_f32_16x16x32_bf16(a, b1, acc1, 0, 0, 0);
    }
    const int n = r0 + wr + quad * 4;
    #pragma unroll
    for (int reg = 0; reg < 4; ++reg) {
        float* o = Lg + (b * 512 + n + reg) * 512 + c0 + wc + mrow;
        o[0]  = acc0[reg] * (1.f / 1024.f);
        o[16] = acc1[reg] * (1.f / 1024.f);
    }
}

// ---------------------------------------------------------------------------
// Kernel 4: softmax over m (512) per row.  Wave per row, 4 rows/block.
// ---------------------------------------------------------------------------
__global__ __launch_bounds__(256) void softmax_kernel(
    const float* __restrict__ Lg, float* __restrict__ attn)
{
    const int row  = blockIdx.x * 4 + (threadIdx.x >> 6);
    const int lane = threadIdx.x & 63;
    const float* L = Lg + row * 512 + 8 * lane;
    float4 x0 = *(const float4*)L;
    float4 x1 = *(const float4*)(L + 4);
    float mx = fmaxf(fmaxf(fmaxf(x0.x, x0.y), fmaxf(x0.z, x0.w)),
                     fmaxf(fmaxf(x1.x, x1.y), fmaxf(x1.z, x1.w)));
    #pragma unroll
    for (int off = 32; off >= 1; off >>= 1) mx = fmaxf(mx, __shfl_xor(mx, off, 64));
    float e[8] = {__expf(x0.x - mx), __expf(x0.y - mx), __expf(x0.z - mx), __expf(x0.w - mx),
                  __expf(x1.x - mx), __expf(x1.y - mx), __expf(x1.z - mx), __expf(x1.w - mx)};
    float s = 0.f;
    #pragma unroll
    for (int i = 0; i < 8; ++i) s += e[i];
    #pragma unroll
    for (int off = 32; off >= 1; off >>= 1) s += __shfl_xor(s, off, 64);
    const float inv = 1.f / s;
    float4 o0 = {e[0] * inv, e[1] * inv, e[2] * inv, e[3] * inv};
    float4 o1 = {e[4] * inv, e[5] * inv, e[6] * inv, e[7] * inv};
    float* A = attn + row * 512 + 8 * lane;
    *(float4*)A = o0;
    *(float4*)(A + 4) = o1;
}

// ---------------------------------------------------------------------------
// Kernel 5 (MFMA): out = base + h * (A @ S).
// which=0: A=attn [n][m], S=txt, base=vis.  which=1: A=attn^T, S=vis, base=txt.
// Tile 32 rows x 64 d-cols, K=512, waves 2x2 of 16x32.  grid (16, 4, 4).
// ---------------------------------------------------------------------------
__global__ __launch_bounds__(256) void out_mfma_kernel(
    const float* __restrict__ vis, const float* __restrict__ txt,
    const float* __restrict__ attn, const float* __restrict__ hptr,
    float* __restrict__ outv, float* __restrict__ outt)
{
    const int z = blockIdx.z;
    const int b = z & 1, which = z >> 1;
    const int r0 = blockIdx.x * 32;
    const int c0 = blockIdx.y * 64;
    const int t = threadIdx.x, lane = t & 63, wave = t >> 6;
    const int wr = (wave >> 1) * 16, wc = (wave & 1) * 32;
    const int mrow = lane & 15, quad = lane >> 4;
    const float hv = hptr[0];

    const float* Ablk = attn + b * N * M;
    const float* S    = (which == 0 ? txt : vis) + b * 512 * D;
    const float* base = (which == 0 ? vis : txt) + b * 512 * D;
    float*       out  = (which == 0 ? outv : outt) + b * 512 * D;

    __shared__ __align__(16) short As[32][40];
    __shared__ __align__(16) short Bs[64][40];

    f32x4 acc0 = {}, acc1 = {};

    for (int k0 = 0; k0 < 512; k0 += 32) {
        __syncthreads();
        if (which == 0) {
            if (t < 128) {
                const int row = t >> 2, ch = t & 3;
                const float* ap = Ablk + (r0 + row) * M + k0 + 8 * ch;
                *(bf16x8*)&As[row][8 * ch] =
                    pack8(*(const float4*)ap, *(const float4*)(ap + 4));
            }
        } else {
            if (t < 128) {               // transpose-stage attn columns
                const int kk = t >> 2, mg = t & 3;
                const float* ap = Ablk + (k0 + kk) * M + r0 + 8 * mg;
                float4 a0 = *(const float4*)ap, a1 = *(const float4*)(ap + 4);
                As[8 * mg + 0][kk] = f2bf(a0.x);
                As[8 * mg + 1][kk] = f2bf(a0.y);
                As[8 * mg + 2][kk] = f2bf(a0.z);
                As[8 * mg + 3][kk] = f2bf(a0.w);
                As[8 * mg + 4][kk] = f2bf(a1.x);
                As[8 * mg + 5][kk] = f2bf(a1.y);
                As[8 * mg + 6][kk] = f2bf(a1.z);
                As[8 * mg + 7][kk] = f2bf(a1.w);
            }
        }
        {                                // B = S^T transpose-stage
            const int kk = t >> 3, cg = t & 7;
            const float* sp = S + (k0 + kk) * D + c0 + 8 * cg;
            float4 s0 = *(const float4*)sp, s1 = *(const float4*)(sp + 4);
            Bs[8 * cg + 0][kk] = f2bf(s0.x);
            Bs[8 * cg + 1][kk] = f2bf(s0.y);
            Bs[8 * cg + 2][kk] = f2bf(s0.z);
            Bs[8 * cg + 3][kk] = f2bf(s0.w);
            Bs[8 * cg + 4][kk] = f2bf(s1.x);
            Bs[8 * cg + 5][kk] = f2bf(s1.y);
            Bs[8 * cg + 6][kk] = f2bf(s1.z);
            Bs[8 * cg + 7][kk] = f2bf(s1.w);
        }
        __syncthreads();
        bf16x8 a  = *(bf16x8*)&As[wr + mrow][8 * quad];
        bf16x8 b0 = *(bf16x8*)&Bs[wc + mrow][8 * quad];
        bf16x8 b1 = *(bf16x8*)&Bs[wc + 16 + mrow][8 * quad];
        acc0 = __builtin_amdgcn_mfma_f32_16x16x32_bf16(a, b0, acc0, 0, 0, 0);
        acc1 = __builtin_amdgcn_mfma_f32_16x16x32_bf16(a, b1, acc1, 0, 0, 0);
    }

    const int n = r0 + wr + quad * 4;
    #pragma unroll
    for (int reg = 0; reg < 4; ++reg) {
        const int row = n + reg;
        const int col = c0 + wc + mrow;
        out[row * D + col]      = fmaf(hv, acc0[reg], base[row * D + col]);
        out[row * D + col + 16] = fmaf(hv, acc1[reg], base[row * D + col + 16]);
    }
}

// ---------------------------------------------------------------------------
extern "C" void kernel_launch(void* const* d_in, const int* in_sizes, int n_in,
                              void* d_out, int out_size, void* d_ws, size_t ws_size,
                              hipStream_t stream)
{
    const float* vis = (const float*)d_in[0];
    const float* txt = (const float*)d_in[1];
    const float* Wv  = (const float*)d_in[2];
    const float* bv  = (const float*)d_in[3];
    const float* Wt  = (const float*)d_in[4];
    const float* bt  = (const float*)d_in[5];
    const float* h   = (const float*)d_in[6];

    float* outv = (float*)d_out;                  // B*N*D
    float* outt = (float*)d_out + B * N * D;      // B*M*D

    float* ws    = (float*)d_ws;
    float* qv    = ws;                            // 1024 x 256  (rows 0..1023)
    float* qt    = ws + 262144;                   // 1024 x 256  (rows 1024..2047)
    float* Lg    = ws + 524288;                   // 1024 x 512 fp32
    float* attn  = ws + 1048576;                  // 1024 x 512 fp32
    short* expq  = (short*)(ws + 1572864);        // 2048 x 1024 bf16 (4 MB)
    short* expv  = expq;
    short* expt  = expq + 1024 * 1024;

    proj_mfma_kernel<<<dim3(16, 4, 2), 256, 0, stream>>>(vis, txt, Wv, bv, Wt, bt, qv, qt);
    expand_kernel<<<dim3(512), 256, 0, stream>>>(qv, expq);
    logits_kernel<<<dim3(16, 8, 2), 256, 0, stream>>>(expv, expt, Lg);
    softmax_kernel<<<dim3(256), 256, 0, stream>>>(Lg, attn);
    out_mfma_kernel<<<dim3(16, 4, 4), 256, 0, stream>>>(vis, txt, attn, h, outv, outt);
}

// Round 6
// 94.087 us; speedup vs baseline: 2.4123x; 1.2106x over previous
//
#include <hip/hip_runtime.h>
#include <math.h>

#define EPS 1e-8f

typedef short bf16x8 __attribute__((ext_vector_type(8)));
typedef short bf16x4 __attribute__((ext_vector_type(4)));
typedef float f32x4  __attribute__((ext_vector_type(4)));

// fp32 -> bf16 bits, round-to-nearest-even
__device__ __forceinline__ short f2bf(float f) {
    union { float fv; unsigned u; } v; v.fv = f;
    unsigned r = v.u + 0x7fffu + ((v.u >> 16) & 1u);
    return (short)(r >> 16);
}
__device__ __forceinline__ float bf2f(short s) {
    union { unsigned u; float f; } v;
    v.u = ((unsigned)(unsigned short)s) << 16;
    return v.f;
}
__device__ __forceinline__ bf16x8 pack8(float4 a, float4 b) {
    bf16x8 p;
    p[0] = f2bf(a.x); p[1] = f2bf(a.y); p[2] = f2bf(a.z); p[3] = f2bf(a.w);
    p[4] = f2bf(b.x); p[5] = f2bf(b.y); p[6] = f2bf(b.z); p[7] = f2bf(b.w);
    return p;
}

// ---------------------------------------------------------------------------
// K1: proj + normalize + FUSED quaternion-pair expand.
// v = normalize4(X @ W^T + b); expq[row][head*16 + i*4 + j] = bf16(q_i * q_j).
// Tile 32 rows x 64 cols, kt=64, K=256 (4 iters).  grid (32, 4, 2), 256 thr.
// Wave = 16x32 C-tile (2x2 wave grid).  C/D layout: col=lane&15, row=quad*4+reg.
// ---------------------------------------------------------------------------
__global__ __launch_bounds__(256) void proj_expand_kernel(
    const float* __restrict__ vis, const float* __restrict__ txt,
    const float* __restrict__ Wv, const float* __restrict__ bv,
    const float* __restrict__ Wt, const float* __restrict__ bt,
    short* __restrict__ expq)
{
    const int which = blockIdx.z;
    const float* X    = which == 0 ? vis : txt;
    const float* W    = which == 0 ? Wv : Wt;
    const float* bias = which == 0 ? bv : bt;
    short* Eo = expq + which * 1024 * 1024;     // 1024 rows x 1024

    const int r0 = blockIdx.x * 32;
    const int c0 = blockIdx.y * 64;
    const int t = threadIdx.x, lane = t & 63, wave = t >> 6;
    const int wr = (wave >> 1) * 16, wc = (wave & 1) * 32;
    const int mrow = lane & 15, quad = lane >> 4;

    __shared__ __align__(16) short As[32][72];   // [row][k]
    __shared__ __align__(16) short Bs[64][72];   // [col][k]

    f32x4 acc[2] = {};

    const int srow = t >> 3, skg = t & 7;
    for (int k0 = 0; k0 < 256; k0 += 64) {
        const float* xp = X + (r0 + srow) * 256 + k0 + 8 * skg;
        float4 xa = *(const float4*)xp, xb = *(const float4*)(xp + 4);
        const float* wp0 = W + (c0 + srow) * 256 + k0 + 8 * skg;
        const float* wp1 = W + (c0 + srow + 32) * 256 + k0 + 8 * skg;
        float4 wa0 = *(const float4*)wp0, wb0 = *(const float4*)(wp0 + 4);
        float4 wa1 = *(const float4*)wp1, wb1 = *(const float4*)(wp1 + 4);
        __syncthreads();
        *(bf16x8*)&As[srow][8 * skg]      = pack8(xa, xb);
        *(bf16x8*)&Bs[srow][8 * skg]      = pack8(wa0, wb0);
        *(bf16x8*)&Bs[srow + 32][8 * skg] = pack8(wa1, wb1);
        __syncthreads();
        #pragma unroll
        for (int kh = 0; kh < 2; ++kh) {
            bf16x8 a  = *(bf16x8*)&As[wr + mrow][32 * kh + 8 * quad];
            bf16x8 b0 = *(bf16x8*)&Bs[wc + mrow][32 * kh + 8 * quad];
            bf16x8 b1 = *(bf16x8*)&Bs[wc + 16 + mrow][32 * kh + 8 * quad];
            acc[0] = __builtin_amdgcn_mfma_f32_16x16x32_bf16(a, b0, acc[0], 0, 0, 0);
            acc[1] = __builtin_amdgcn_mfma_f32_16x16x32_bf16(a, b1, acc[1], 0, 0, 0);
        }
    }

    const int qbase = lane & ~3;                 // 4 lanes holding this quaternion
    #pragma unroll
    for (int j = 0; j < 2; ++j) {
        const int col  = c0 + wc + 16 * j + mrow;
        const float bb = bias[col];
        const int head = col >> 2;
        #pragma unroll
        for (int reg = 0; reg < 4; ++reg) {
            const int row = r0 + wr + quad * 4 + reg;
            float v = acc[j][reg] + bb;
            float s = v * v;
            s += __shfl_xor(s, 1, 64);
            s += __shfl_xor(s, 2, 64);
            float q = v * (1.f / (sqrtf(s) + EPS));
            // ordered components via dynamic-lane shuffles (ds_bpermute)
            float q0 = __shfl(q, qbase + 0, 64);
            float q1 = __shfl(q, qbase + 1, 64);
            float q2 = __shfl(q, qbase + 2, 64);
            float q3 = __shfl(q, qbase + 3, 64);
            bf16x4 p;
            p[0] = f2bf(q * q0); p[1] = f2bf(q * q1);
            p[2] = f2bf(q * q2); p[3] = f2bf(q * q3);
            *(bf16x4*)(Eo + row * 1024 + head * 16 + (col & 3) * 4) = p;
        }
    }
}

// ---------------------------------------------------------------------------
// K2: E[n][m] = exp(dot(expv_n, expt_m)/1024)  (logits in [0,1/16] -> no max
// subtraction needed), bf16; plus partial row sums rs[row][16] (fp32, one per
// 32-col slab).  Tile 32(n) x 64(m), kt=64, K=1024.  grid (16, 8, 2).
// ---------------------------------------------------------------------------
__global__ __launch_bounds__(256) void logits_kernel(
    const short* __restrict__ expq, short* __restrict__ E,
    float* __restrict__ rs)
{
    const int b  = blockIdx.z;
    const int r0 = blockIdx.x * 32;
    const int c0 = blockIdx.y * 64;
    const int t = threadIdx.x, lane = t & 63, wave = t >> 6;
    const int wr = (wave >> 1) * 16, wc = (wave & 1) * 32;
    const int mrow = lane & 15, quad = lane >> 4;

    __shared__ __align__(16) short As[32][72];
    __shared__ __align__(16) short Bs[64][72];

    const short* Abase = expq + (b * 512 + r0) * 1024;
    const short* Bbase = expq + (1024 + b * 512 + c0) * 1024;

    f32x4 acc[2] = {};
    const int srow = t >> 3, skg = t & 7;
    for (int k0 = 0; k0 < 1024; k0 += 64) {
        bf16x8 av = *(const bf16x8*)(Abase + srow * 1024 + k0 + 8 * skg);
        bf16x8 b0v = *(const bf16x8*)(Bbase + srow * 1024 + k0 + 8 * skg);
        bf16x8 b1v = *(const bf16x8*)(Bbase + (srow + 32) * 1024 + k0 + 8 * skg);
        __syncthreads();
        *(bf16x8*)&As[srow][8 * skg]      = av;
        *(bf16x8*)&Bs[srow][8 * skg]      = b0v;
        *(bf16x8*)&Bs[srow + 32][8 * skg] = b1v;
        __syncthreads();
        #pragma unroll
        for (int kh = 0; kh < 2; ++kh) {
            bf16x8 a  = *(bf16x8*)&As[wr + mrow][32 * kh + 8 * quad];
            bf16x8 b0 = *(bf16x8*)&Bs[wc + mrow][32 * kh + 8 * quad];
            bf16x8 b1 = *(bf16x8*)&Bs[wc + 16 + mrow][32 * kh + 8 * quad];
            acc[0] = __builtin_amdgcn_mfma_f32_16x16x32_bf16(a, b0, acc[0], 0, 0, 0);
            acc[1] = __builtin_amdgcn_mfma_f32_16x16x32_bf16(a, b1, acc[1], 0, 0, 0);
        }
    }

    float e[2][4];
    #pragma unroll
    for (int j = 0; j < 2; ++j)
        #pragma unroll
        for (int reg = 0; reg < 4; ++reg)
            e[j][reg] = __expf(acc[j][reg] * (1.f / 1024.f));

    #pragma unroll
    for (int j = 0; j < 2; ++j) {
        const int col = c0 + wc + 16 * j + mrow;
        #pragma unroll
        for (int reg = 0; reg < 4; ++reg) {
            const int row = r0 + wr + quad * 4 + reg;
            E[(b * 512 + row) * 512 + col] = f2bf(e[j][reg]);
        }
    }
    // partial sums over this wave's 32 cols -> rs[row][c0/32 + wc/32]
    #pragma unroll
    for (int reg = 0; reg < 4; ++reg) {
        float p = e[0][reg] + e[1][reg];
        p += __shfl_xor(p, 1, 64);
        p += __shfl_xor(p, 2, 64);
        p += __shfl_xor(p, 4, 64);
        p += __shfl_xor(p, 8, 64);
        if (mrow == 0) {
            const int row = r0 + wr + quad * 4 + reg;
            rs[(b * 512 + row) * 16 + (c0 >> 5) + (wc >> 5)] = p;
        }
    }
}

// ---------------------------------------------------------------------------
// K3: out = base + h * softmax-normalized attention product.
// which=0: out_v[n][d] = vis + h*rinv_n * sum_m E[n][m]*txt[m][d]
//          (rinv applied in EPILOGUE - A staged raw)
// which=1: out_t[m][d] = txt + h * sum_n (E[n][m]*rinv_n)*vis[n][d]
//          (rinv applied during transpose-STAGING - per-k scale)
// rinv computed in prologue from rs partials.  Tile 32 x 64(d), kt=64, K=512.
// grid (16, 4, 4) = (row-tile, d-tile, b + 2*which).
// ---------------------------------------------------------------------------
__global__ __launch_bounds__(256) void out_kernel(
    const float* __restrict__ vis, const float* __restrict__ txt,
    const short* __restrict__ E, const float* __restrict__ rs,
    const float* __restrict__ hptr,
    float* __restrict__ outv, float* __restrict__ outt)
{
    const int z = blockIdx.z;
    const int b = z & 1, which = z >> 1;
    const int r0 = blockIdx.x * 32;
    const int c0 = blockIdx.y * 64;
    const int t = threadIdx.x, lane = t & 63, wave = t >> 6;
    const int wr = (wave >> 1) * 16, wc = (wave & 1) * 32;
    const int mrow = lane & 15, quad = lane >> 4;
    const float hv = hptr[0];

    const short* Eb   = E + b * 512 * 512;
    const float* S    = (which == 0 ? txt : vis) + b * 512 * 256;
    const float* base = (which == 0 ? vis : txt) + b * 512 * 256;
    float*       out  = (which == 0 ? outv : outt) + b * 512 * 256;

    __shared__ __align__(16) short As[32][72];
    __shared__ __align__(16) short Bs[64][72];
    __shared__ float rinv_s[512];

    #pragma unroll
    for (int u = 0; u < 2; ++u) {            // 1/rowsum for all 512 rows of b
        const int row = t + 256 * u;
        const float* p = rs + (b * 512 + row) * 16;
        float s = 0.f;
        #pragma unroll
        for (int i = 0; i < 16; ++i) s += p[i];
        rinv_s[row] = 1.f / s;
    }
    __syncthreads();

    f32x4 acc[2] = {};
    const int kkB = t >> 3, cg = t & 7;      // B staging coords
    const int rowA = t >> 3, kgA = t & 7;    // A direct (which=0)
    const int nnA = t >> 2, mgA = t & 3;     // A transpose (which=1)

    for (int k0 = 0; k0 < 512; k0 += 64) {
        float4 sa[2], sb[2];
        #pragma unroll
        for (int u = 0; u < 2; ++u) {
            const float* sp = S + (k0 + kkB + 32 * u) * 256 + c0 + 8 * cg;
            sa[u] = *(const float4*)sp; sb[u] = *(const float4*)(sp + 4);
        }
        bf16x8 arow;
        float af[8];
        if (which == 0) {
            arow = *(const bf16x8*)(Eb + (r0 + rowA) * 512 + k0 + 8 * kgA);
        } else {
            bf16x8 ev = *(const bf16x8*)(Eb + (k0 + nnA) * 512 + r0 + 8 * mgA);
            const float ri = rinv_s[k0 + nnA];
            #pragma unroll
            for (int c = 0; c < 8; ++c) af[c] = bf2f(ev[c]) * ri;
        }
        __syncthreads();
        if (which == 0) {
            *(bf16x8*)&As[rowA][8 * kgA] = arow;
        } else {
            #pragma unroll
            for (int c = 0; c < 8; ++c) As[8 * mgA + c][nnA] = f2bf(af[c]);
        }
        #pragma unroll
        for (int u = 0; u < 2; ++u) {
            const int kk = kkB + 32 * u;
            Bs[8 * cg + 0][kk] = f2bf(sa[u].x);
            Bs[8 * cg + 1][kk] = f2bf(sa[u].y);
            Bs[8 * cg + 2][kk] = f2bf(sa[u].z);
            Bs[8 * cg + 3][kk] = f2bf(sa[u].w);
            Bs[8 * cg + 4][kk] = f2bf(sb[u].x);
            Bs[8 * cg + 5][kk] = f2bf(sb[u].y);
            Bs[8 * cg + 6][kk] = f2bf(sb[u].z);
            Bs[8 * cg + 7][kk] = f2bf(sb[u].w);
        }
        __syncthreads();
        #pragma unroll
        for (int kh = 0; kh < 2; ++kh) {
            bf16x8 a  = *(bf16x8*)&As[wr + mrow][32 * kh + 8 * quad];
            bf16x8 b0 = *(bf16x8*)&Bs[wc + mrow][32 * kh + 8 * quad];
            bf16x8 b1 = *(bf16x8*)&Bs[wc + 16 + mrow][32 * kh + 8 * quad];
            acc[0] = __builtin_amdgcn_mfma_f32_16x16x32_bf16(a, b0, acc[0], 0, 0, 0);
            acc[1] = __builtin_amdgcn_mfma_f32_16x16x32_bf16(a, b1, acc[1], 0, 0, 0);
        }
    }

    #pragma unroll
    for (int j = 0; j < 2; ++j) {
        const int col = c0 + wc + 16 * j + mrow;
        #pragma unroll
        for (int reg = 0; reg < 4; ++reg) {
            const int row = r0 + wr + quad * 4 + reg;
            const float scale = which == 0 ? hv * rinv_s[row] : hv;
            out[row * 256 + col] = fmaf(scale, acc[j][reg], base[row * 256 + col]);
        }
    }
}

// ---------------------------------------------------------------------------
extern "C" void kernel_launch(void* const* d_in, const int* in_sizes, int n_in,
                              void* d_out, int out_size, void* d_ws, size_t ws_size,
                              hipStream_t stream)
{
    const float* vis = (const float*)d_in[0];
    const float* txt = (const float*)d_in[1];
    const float* Wv  = (const float*)d_in[2];
    const float* bv  = (const float*)d_in[3];
    const float* Wt  = (const float*)d_in[4];
    const float* bt  = (const float*)d_in[5];
    const float* h   = (const float*)d_in[6];

    float* outv = (float*)d_out;                  // 2*512*256
    float* outt = (float*)d_out + 2 * 512 * 256;

    short* expq = (short*)d_ws;                   // 2048 x 1024 bf16 (4 MB)
    short* E    = expq + 2048 * 1024;             // 1024 x 512 bf16 (1 MB)
    float* rs   = (float*)(E + 1024 * 512);       // 1024 x 16 fp32 (64 KB)

    proj_expand_kernel<<<dim3(32, 4, 2), 256, 0, stream>>>(vis, txt, Wv, bv, Wt, bt, expq);
    logits_kernel<<<dim3(16, 8, 2), 256, 0, stream>>>(expq, E, rs);
    out_kernel<<<dim3(16, 4, 4), 256, 0, stream>>>(vis, txt, E, rs, h, outv, outt);
}